// Round 2
// baseline (495.327 us; speedup 1.0000x reference)
//
#include <hip/hip_runtime.h>
#include <math.h>

typedef unsigned long long u64;
typedef unsigned int u32;

#define B_ 8
#define N_ 1000
#define C_ 81
#define NC 80          // C-1 (background dropped)
#define K_ 100
#define M_ 28
#define IMG_W_ 1216.0f
#define IMG_H_ 800.0f
#define SCORE_TH 0.05f
#define NMS_TH 0.5f
#define BBOX_CLIP 4.135166556742356f  // log(1000/16)
#define CAP 80000      // worst-case survivors per image
// bucket = key>>44 = score_bits>>17 (top 15 bits: sign+exp+6 mantissa).
// score in (0.05, 1.0]: 0x3D4CCCCD>>17 = 0x1EA6 .. 0x3F800000>>17 = 0x1FC0 -> 283 buckets.
#define BUCKET_BASE 0x1EA6
#define NBUCKET 320

// ---- fused-launch geometry (roles assigned by ARRIVAL ticket, not blockIdx) ----
#define SCORE_BLKS 2000            // 4 rows each -> 8000 rows; 250 blocks/image
#define NMS_BLKS   160             // 4 (b,c) pairs each (one per wave); 20 blocks/image
#define TOPK_BLKS  8
#define MASK_BLKS  613             // ceil(8*100*196 / 256) float4 units
#define TOTAL_BLKS (SCORE_BLKS + NMS_BLKS + TOPK_BLKS + MASK_BLKS)

// Persistent device state: zero at module load; the LAST mask block re-zeroes
// everything after all consumers are done, so every launch (incl. graph and
// rocprof replays) starts from zeroed state.
__device__ int g_ticket;
__device__ int g_score_done[B_];   // -> 250 each
__device__ int g_nms_done[B_];     // -> 20 each
__device__ int g_topk_done;        // -> 8
__device__ int g_mask_done;        // -> MASK_BLKS
__device__ int g_pc_cnt[B_ * NC];
__device__ int g_counts[B_];

// workspace layout (bytes):
// [0, 5120000)          gkeys    u64[8*80000]
// [5120000, 10240000)   pc_keys  u64[640*1000]

__device__ __forceinline__ void decode_box(const float* __restrict__ box_reg,
                                           const float* __restrict__ props,
                                           int row, int cls, float* o) {
    const float* pr = props + row * 4;
    float x1 = pr[0], y1 = pr[1], x2 = pr[2], y2 = pr[3];
    float w = x2 - x1, h = y2 - y1;
    float cx = x1 + 0.5f * w, cy = y1 + 0.5f * h;
    const float* r = box_reg + (size_t)row * (C_ * 4) + cls * 4;
    float dx = r[0] / 10.f, dy = r[1] / 10.f;
    float dw = fminf(r[2] / 5.f, BBOX_CLIP);
    float dh = fminf(r[3] / 5.f, BBOX_CLIP);
    float pcx = dx * w + cx, pcy = dy * h + cy;
    float pw = expf(dw) * w, ph = expf(dh) * h;
    o[0] = fminf(fmaxf(pcx - 0.5f * pw, 0.f), IMG_W_);
    o[1] = fminf(fmaxf(pcy - 0.5f * ph, 0.f), IMG_H_);
    o[2] = fminf(fmaxf(pcx + 0.5f * pw, 0.f), IMG_W_);
    o[3] = fminf(fmaxf(pcy + 0.5f * ph, 0.f), IMG_H_);
}

__device__ __forceinline__ void emit_det(int b, int k, u64 key,
                                         const float* __restrict__ box_reg,
                                         const float* __restrict__ props,
                                         float* __restrict__ out) {
    float* ob = out + (b * K_ + k) * 4;
    if (key == 0) {
        ob[0] = 0.f; ob[1] = 0.f; ob[2] = 0.f; ob[3] = 0.f;
        out[3200 + b * K_ + k] = 0.f;
        out[4000 + b * K_ + k] = 0.f;
        return;
    }
    u32 sb = (u32)(key >> 27);
    int flat = 0x1FFFF - (int)((key >> 10) & 0x1FFFF);
    int n = (int)(key & 1023);
    int c = flat / 1000;   // class-1
    float bx[4];
    decode_box(box_reg, props, b * N_ + n, c + 1, bx);
    ob[0] = bx[0]; ob[1] = bx[1]; ob[2] = bx[2]; ob[3] = bx[3];
    out[3200 + b * K_ + k] = __uint_as_float(sb);
    out[4000 + b * K_ + k] = (float)(c + 1);
}

// ---- device-scope release/acquire helpers (cross-XCD safe: G16) ----
__device__ __forceinline__ void wait_ge(int* p, int target) {
    if (threadIdx.x == 0) {
        while (atomicAdd(p, 0) < target) __builtin_amdgcn_s_sleep(8);
    }
    __syncthreads();
    __threadfence();           // acquire: invalidate L1/L2 before consuming
}

__device__ __forceinline__ void mark_done(int* p) {
    __syncthreads();           // all waves' stores issued
    if (threadIdx.x == 0) {
        __threadfence();       // release: writeback L2 so peers see data
        atomicAdd(p, 1);
    }
}

// ------------- single-wave in-register bitonic (descending), SS = R*64 -------------
// element index i = (r<<6)|lane. j>=64 exchanges are compile-time register pairs
// (no runtime register indexing -> no scratch); j<64 exchanges via shfl_xor.
template <int R, int JR>
__device__ __forceinline__ void reg_step(u64 (&k)[R], int k2, int lane) {
    #pragma unroll
    for (int r = 0; r < R; ++r) {
        if ((r & JR) == 0 && (r | JR) < R) {
            const int r2 = r | JR;
            int i = (r << 6) | lane;
            bool desc = (i & k2) == 0;
            u64 a = k[r], bb = k[r2];
            if (desc ? (a < bb) : (a > bb)) { k[r] = bb; k[r2] = a; }
        }
    }
}

template <int R>
__device__ __forceinline__ void wave_sort_topk(u64* comp, int cc, int lane) {
    u64 k[R];
    #pragma unroll
    for (int r = 0; r < R; ++r) {
        int idx = (r << 6) | lane;
        k[r] = (idx < cc) ? comp[idx] : 0ull;
    }
    const int SS = R * 64;
    #pragma unroll
    for (int k2 = 2; k2 <= SS; k2 <<= 1) {
        if (k2 >= 512) reg_step<R, 4>(k, k2, lane);   // j = 256
        if (k2 >= 256) reg_step<R, 2>(k, k2, lane);   // j = 128
        if (k2 >= 128) reg_step<R, 1>(k, k2, lane);   // j = 64
        for (int j = (k2 > 64 ? 32 : (k2 >> 1)); j > 0; j >>= 1) {
            #pragma unroll
            for (int r = 0; r < R; ++r) {
                u64 p = __shfl_xor(k[r], j);
                int i = (r << 6) | lane;
                bool lower = (lane & j) == 0;
                bool desc = (i & k2) == 0;
                u64 mx = k[r] > p ? k[r] : p;
                u64 mn = k[r] > p ? p : k[r];
                k[r] = (lower == desc) ? mx : mn;
            }
        }
    }
    // write back top-128 (covers K_=100); rest of comp is never read
    comp[lane] = k[0];
    comp[64 | lane] = k[1];
}

// ---- shared-memory union: phases are mutually exclusive per block ----
struct SmNms  { u64 skeys[1024]; float sbx[1024][4]; unsigned char skeep[1024]; };   // 25.6 KB
struct SmTopk { u64 comp[2048]; int hist[NBUCKET]; };                                 // 17.7 KB
union SMem { SmNms nms; SmTopk topk; };

// =======================  THE fused kernel  =======================
__global__ __launch_bounds__(256) void k_all(const float* __restrict__ logits,
                                             const float* __restrict__ box_reg,
                                             const float* __restrict__ props,
                                             const float* __restrict__ mask_logits,
                                             float* __restrict__ out,
                                             u64* __restrict__ gkeys,
                                             u64* __restrict__ pc_keys) {
    __shared__ SMem sm;
    __shared__ int s_ticket, sT, sCompCnt, s_ncold;
    __shared__ int s_cold[4];
    __shared__ u64 wk[4];
    __shared__ int wp[4];

    int tid = threadIdx.x;
    if (tid == 0) s_ticket = atomicAdd(&g_ticket, 1);
    __syncthreads();
    int t = s_ticket;

    if (t < SCORE_BLKS) {
        // ================= PHASE 1: softmax + threshold + per-class compaction ====
        int wave = tid >> 6, lane = tid & 63;
        int row = t * 4 + wave;                     // [0, 8000)
        const float* lg = logits + row * C_;
        float v0 = lg[lane];
        float v1 = (lane < C_ - 64) ? lg[lane + 64] : -INFINITY;
        float m = fmaxf(v0, v1);
        #pragma unroll
        for (int o = 32; o; o >>= 1) m = fmaxf(m, __shfl_xor(m, o));
        float e0 = expf(v0 - m);
        float e1 = (lane < C_ - 64) ? expf(v1 - m) : 0.f;
        float s = e0 + e1;
        #pragma unroll
        for (int o = 32; o; o >>= 1) s += __shfl_xor(s, o);
        float inv = 1.f / s;
        int b = row / N_, n = row % N_;
        float s0 = e0 * inv;            // class = lane (lane>=1; lane 0 is background)
        if (lane >= 1 && s0 > SCORE_TH) {
            int idx = b * NC + (lane - 1);
            int p = atomicAdd(&g_pc_cnt[idx], 1);
            pc_keys[(size_t)idx * 1000 + p] =
                ((u64)__float_as_uint(s0) << 10) | (u32)(1023 - n);
        }
        float s1 = e1 * inv;            // class = lane + 64
        if (lane < C_ - 64 && s1 > SCORE_TH) {
            int idx = b * NC + (lane + 63);
            int p = atomicAdd(&g_pc_cnt[idx], 1);
            pc_keys[(size_t)idx * 1000 + p] =
                ((u64)__float_as_uint(s1) << 10) | (u32)(1023 - n);
        }
        mark_done(&g_score_done[t / 250]);          // 250 score blocks per image

    } else if (t < SCORE_BLKS + NMS_BLKS) {
        // ================= PHASE 2: per-(b,c) sort + NMS (one pair per wave) ======
        int u = t - SCORE_BLKS;                     // [0,160); 20 per image
        int b_img = u / 20;
        if (tid == 0) s_ncold = 0;
        wait_ge(&g_score_done[b_img], 250);

        int wave = tid >> 6, lane = tid & 63;
        int bc = u * 4 + wave;                      // all 4 pairs share b_img
        int b = bc / NC, c = bc % NC;               // class id = c+1
        int cnt = g_pc_cnt[bc];
        const u64* pk = pc_keys + (size_t)bc * 1000;

        if (cnt <= 64) {
            // ---- fast path: registers only, zero barriers, per-wave ----
            u64 key = (lane < cnt) ? pk[lane] : 0;
            #pragma unroll
            for (int k2 = 2; k2 <= 64; k2 <<= 1) {
                #pragma unroll
                for (int j = k2 >> 1; j; j >>= 1) {
                    u64 p = __shfl_xor(key, j);
                    bool takeMax = ((lane & j) == 0) == ((lane & k2) == 0);
                    bool greater = key > p;
                    key = (takeMax == greater) ? key : p;
                }
            }
            float x1 = 0.f, y1 = 0.f, x2 = 0.f, y2 = 0.f, area = 0.f;
            int n = 1023 - (int)(key & 1023);
            u32 sb = (u32)(key >> 10);
            if (lane < cnt) {
                float bx[4];
                decode_box(box_reg, props, b * N_ + n, c + 1, bx);
                x1 = bx[0]; y1 = bx[1]; x2 = bx[2]; y2 = bx[3];
                area = (x2 - x1) * (y2 - y1);
            }
            u64 keepm = (cnt >= 64) ? ~0ull : ((1ull << cnt) - 1ull);
            for (int i = 0; i < cnt; ++i) {
                if (!((keepm >> i) & 1ull)) continue;
                float ax1 = __shfl(x1, i), ay1 = __shfl(y1, i);
                float ax2 = __shfl(x2, i), ay2 = __shfl(y2, i);
                float aarea = __shfl(area, i);
                float lx = fmaxf(ax1, x1), ly = fmaxf(ay1, y1);
                float rx = fminf(ax2, x2), ry = fminf(ay2, y2);
                float iw = fmaxf(rx - lx, 0.f), ih = fmaxf(ry - ly, 0.f);
                float inter = iw * ih;
                float iou = inter / (aarea + area - inter + 1e-9f);
                bool sup = (lane > i) && (lane < cnt) && (iou > NMS_TH);
                keepm &= ~__ballot(sup);
            }
            int total = __popcll(keepm);
            int base = 0;
            if (lane == 0 && total) base = atomicAdd(&g_counts[b], total);
            base = __shfl(base, 0);
            if ((keepm >> lane) & 1ull) {
                int off = __popcll(keepm & ((1ull << lane) - 1ull));
                int flat = c * 1000 + lane;
                gkeys[(size_t)b * CAP + base + off] =
                    ((u64)sb << 27) | ((u64)(0x1FFFF - flat) << 10) | (u32)n;
            }
        } else {
            if (lane == 0) { int p = atomicAdd(&s_ncold, 1); s_cold[p] = bc; }
        }
        __syncthreads();
        // ---- improbable cold pairs: block-wide LDS bitonic + sequential NMS ----
        for (int ci = 0; ci < s_ncold; ++ci) {
            int bc2 = s_cold[ci];
            int b2 = bc2 / NC, c2 = bc2 % NC;
            int cnt2 = g_pc_cnt[bc2];
            const u64* pk2 = pc_keys + (size_t)bc2 * 1000;
            for (int i = tid; i < 1024; i += 256) sm.nms.skeys[i] = (i < cnt2) ? pk2[i] : 0;
            __syncthreads();
            for (int k2 = 2; k2 <= 1024; k2 <<= 1) {
                for (int j = k2 >> 1; j; j >>= 1) {
                    for (int i = tid; i < 1024; i += 256) {
                        int ixj = i ^ j;
                        if (ixj > i) {
                            u64 a = sm.nms.skeys[i], bb2 = sm.nms.skeys[ixj];
                            bool desc = ((i & k2) == 0);
                            if (desc ? (a < bb2) : (a > bb2)) {
                                sm.nms.skeys[i] = bb2; sm.nms.skeys[ixj] = a;
                            }
                        }
                    }
                    __syncthreads();
                }
            }
            for (int i = tid; i < cnt2; i += 256) {
                u64 key = sm.nms.skeys[i];
                int n = 1023 - (int)(key & 1023);
                decode_box(box_reg, props, b2 * N_ + n, c2 + 1, sm.nms.sbx[i]);
                sm.nms.skeep[i] = 1;
            }
            __syncthreads();
            for (int i = 0; i < cnt2; ++i) {
                if (sm.nms.skeep[i]) {
                    float ax1 = sm.nms.sbx[i][0], ay1 = sm.nms.sbx[i][1];
                    float ax2 = sm.nms.sbx[i][2], ay2 = sm.nms.sbx[i][3];
                    float a1 = (ax2 - ax1) * (ay2 - ay1);
                    for (int j = i + 1 + tid; j < cnt2; j += 256) {
                        float lx = fmaxf(ax1, sm.nms.sbx[j][0]), ly = fmaxf(ay1, sm.nms.sbx[j][1]);
                        float rx = fminf(ax2, sm.nms.sbx[j][2]), ry = fminf(ay2, sm.nms.sbx[j][3]);
                        float iw = fmaxf(rx - lx, 0.f), ih = fmaxf(ry - ly, 0.f);
                        float inter = iw * ih;
                        float a2 = (sm.nms.sbx[j][2] - sm.nms.sbx[j][0]) *
                                   (sm.nms.sbx[j][3] - sm.nms.sbx[j][1]);
                        float iou = inter / (a1 + a2 - inter + 1e-9f);
                        if (iou > NMS_TH) sm.nms.skeep[j] = 0;
                    }
                }
                __syncthreads();
            }
            for (int i = tid; i < cnt2; i += 256) {
                if (sm.nms.skeep[i]) {
                    int p2 = atomicAdd(&g_counts[b2], 1);
                    u64 key = sm.nms.skeys[i];
                    u32 sb = (u32)(key >> 10);
                    int n = 1023 - (int)(key & 1023);
                    int flat = c2 * 1000 + i;
                    gkeys[(size_t)b2 * CAP + p2] =
                        ((u64)sb << 27) | ((u64)(0x1FFFF - flat) << 10) | (u32)n;
                }
            }
            __syncthreads();
        }
        mark_done(&g_nms_done[b_img]);

    } else if (t < SCORE_BLKS + NMS_BLKS + TOPK_BLKS) {
        // ================= PHASE 3: per-image top-K (histogram select + sort) =====
        int b = t - (SCORE_BLKS + NMS_BLKS);
        wait_ge(&g_nms_done[b], 20);
        int cnt = g_counts[b];
        if (cnt > CAP) cnt = CAP;
        u64* gk = gkeys + (size_t)b * CAP;

        for (int i = tid; i < NBUCKET; i += 256) sm.topk.hist[i] = 0;
        if (tid == 0) sCompCnt = 0;
        __syncthreads();
        // pass A: histogram of the monotone 15-bit score prefix (key>>44)
        for (int i = tid; i < cnt; i += 256) {
            int bk = (int)(gk[i] >> 44) - BUCKET_BASE;
            bk = min(max(bk, 0), NBUCKET - 1);
            atomicAdd(&sm.topk.hist[bk], 1);
        }
        __syncthreads();
        // single-wave suffix scan: smallest T with count(bucket>=T) >= K
        if (tid < 64) {
            int lane = tid;
            int running = 0, T = 0;
            for (int step = 0; step < NBUCKET / 64; ++step) {
                int bucket = NBUCKET - 1 - (step * 64 + lane);
                int v = sm.topk.hist[bucket];
                #pragma unroll
                for (int o = 1; o < 64; o <<= 1) {
                    int tu = __shfl_up(v, o);
                    if (lane >= o) v += tu;
                }
                int cum = running + v;
                u64 mask = __ballot(cum >= K_);
                if (mask) {
                    int fl = __ffsll(mask) - 1;   // first (highest-bucket) crossing
                    T = NBUCKET - 1 - (step * 64 + fl);
                    break;
                }
                running = __shfl(cum, 63);
            }
            if (tid == 0) sT = T;
        }
        __syncthreads();
        int T = sT;
        // pass B: compact keys with bucket >= T (superset of top-K, ~100-300)
        for (int i = tid; i < cnt; i += 256) {
            u64 key = gk[i];
            int bk = (int)(key >> 44) - BUCKET_BASE;
            bk = min(max(bk, 0), NBUCKET - 1);
            if (bk >= T) {
                int p = atomicAdd(&sCompCnt, 1);
                if (p < 2048) sm.topk.comp[p] = key;
            }
        }
        __syncthreads();
        int cc = sCompCnt;
        if (cc <= 2048) {
            if (cc <= 128) {
                if (tid < 64) wave_sort_topk<2>(sm.topk.comp, cc, tid);
            } else if (cc <= 256) {
                if (tid < 64) wave_sort_topk<4>(sm.topk.comp, cc, tid);
            } else if (cc <= 512) {
                if (tid < 64) wave_sort_topk<8>(sm.topk.comp, cc, tid);
            } else {
                int SS = (cc > 1024) ? 2048 : 1024;
                for (int i = cc + tid; i < SS; i += 256) sm.topk.comp[i] = 0;
                __syncthreads();
                for (int k2 = 2; k2 <= SS; k2 <<= 1) {
                    for (int j = k2 >> 1; j; j >>= 1) {
                        for (int i = tid; i < SS; i += 256) {
                            int ixj = i ^ j;
                            if (ixj > i) {
                                u64 a = sm.topk.comp[i], bb2 = sm.topk.comp[ixj];
                                bool desc = ((i & k2) == 0);
                                if (desc ? (a < bb2) : (a > bb2)) {
                                    sm.topk.comp[i] = bb2; sm.topk.comp[ixj] = a;
                                }
                            }
                        }
                        __syncthreads();
                    }
                }
            }
            __syncthreads();
            if (tid < K_) emit_det(b, tid, sm.topk.comp[tid], box_reg, props, out);
        } else {
            // vanishingly improbable: destructive iterative argmax over gk
            for (int k = 0; k < K_; ++k) {
                u64 best = 0; int bpos = 0;
                for (int i = tid; i < cnt; i += 256) {
                    u64 v = gk[i];
                    if (v > best) { best = v; bpos = i; }
                }
                for (int o = 32; o; o >>= 1) {
                    u64 ov = __shfl_down(best, o);
                    int op = __shfl_down(bpos, o);
                    if (ov > best) { best = ov; bpos = op; }
                }
                if ((tid & 63) == 0) { wk[tid >> 6] = best; wp[tid >> 6] = bpos; }
                __syncthreads();
                if (tid == 0) {
                    for (int w2 = 1; w2 < 4; ++w2)
                        if (wk[w2] > best) { best = wk[w2]; bpos = wp[w2]; }
                    emit_det(b, k, best, box_reg, props, out);
                    if (best) gk[bpos] = 0;
                }
                __threadfence();
                __syncthreads();
            }
        }
        mark_done(&g_topk_done);

    } else {
        // ================= PHASE 4: mask sigmoid gather (float4) ==================
        int u = t - (SCORE_BLKS + NMS_BLKS + TOPK_BLKS);
        wait_ge(&g_topk_done, TOPK_BLKS);
        int idx = u * 256 + tid;                    // over B*K*196 float4s
        if (idx < B_ * K_ * 196) {
            int p = idx % 196;
            int bk = idx / 196;                     // b*K + k
            int label = (int)out[4000 + bk];        // exact small-int float
            const float4* src = (const float4*)mask_logits;
            float4 v = src[((size_t)bk * C_ + label) * 196 + p];
            float4 r;
            r.x = 1.f / (1.f + expf(-v.x));
            r.y = 1.f / (1.f + expf(-v.y));
            r.z = 1.f / (1.f + expf(-v.z));
            r.w = 1.f / (1.f + expf(-v.w));
            ((float4*)(out + 4800))[idx] = r;
        }
        // last mask block to finish resets ALL device state for the next launch
        __syncthreads();
        if (tid == 0) {
            __threadfence();
            int old = atomicAdd(&g_mask_done, 1);
            if (old == MASK_BLKS - 1) {
                for (int i = 0; i < B_ * NC; ++i) g_pc_cnt[i] = 0;
                for (int i = 0; i < B_; ++i) {
                    g_counts[i] = 0; g_score_done[i] = 0; g_nms_done[i] = 0;
                }
                g_topk_done = 0;
                g_mask_done = 0;
                g_ticket = 0;
                __threadfence();
            }
        }
    }
}

extern "C" void kernel_launch(void* const* d_in, const int* in_sizes, int n_in,
                              void* d_out, int out_size, void* d_ws, size_t ws_size,
                              hipStream_t stream) {
    const float* logits   = (const float*)d_in[0];  // [B*N, C]
    const float* box_reg  = (const float*)d_in[1];  // [B*N, C*4]
    const float* props    = (const float*)d_in[2];  // [B, N, 4]
    const float* mask_log = (const float*)d_in[3];  // [B, K, C, M, M]
    float* out = (float*)d_out;

    char* ws = (char*)d_ws;
    u64* gkeys   = (u64*)ws;                  // 8*80000 u64
    u64* pc_keys = (u64*)(ws + 5120000);      // 640*1000 u64

    k_all<<<TOTAL_BLKS, 256, 0, stream>>>(logits, box_reg, props, mask_log,
                                          out, gkeys, pc_keys);
}

// Round 3
// 271.857 us; speedup vs baseline: 1.8220x; 1.8220x over previous
//
#include <hip/hip_runtime.h>
#include <math.h>

typedef unsigned long long u64;
typedef unsigned int u32;

#define B_ 8
#define N_ 1000
#define C_ 81
#define NC 80          // C-1 (background dropped)
#define K_ 100
#define M_ 28
#define IMG_W_ 1216.0f
#define IMG_H_ 800.0f
#define SCORE_TH 0.05f
#define NMS_TH 0.5f
#define BBOX_CLIP 4.135166556742356f  // log(1000/16)
#define CAP 80000      // worst-case survivors per image
// bucket = key>>44 = score_bits>>17 (top 15 bits: sign+exp+6 mantissa).
// score in (0.05, 1.0]: 0x3D4CCCCD>>17 = 0x1EA6 .. 0x3F800000>>17 = 0x1FC0 -> 283 buckets.
#define BUCKET_BASE 0x1EA6
#define NBUCKET 320

// Persistent counters: zero-initialized at module load, re-zeroed at the END of
// every k_topk launch (after all consumers are done). This removes the
// hipMemsetAsync graph node. Safe across graph replays / rocprof replays
// because every execution leaves them zeroed.
// NOTE (R2 lesson): cross-block sync stays at KERNEL BOUNDARIES. Intra-kernel
// device-scope fences/spins cost ~0.1 us x #blocks on gfx950 (L2 wb/inv per
// fence, serialized coherent-point atomics) -> fused single-launch was 10x slower.
__device__ int g_pc_cnt[B_ * NC];
__device__ int g_counts[B_];

// workspace layout (bytes):
// [0, 5120000)          gkeys    u64[8*80000]
// [5120000, 10240000)   pc_keys  u64[640*1000]
// (never pre-zeroed: only entries within the per-launch counts are ever read)

__device__ __forceinline__ void decode_box(const float* __restrict__ box_reg,
                                           const float* __restrict__ props,
                                           int row, int cls, float* o) {
    const float* pr = props + row * 4;
    float x1 = pr[0], y1 = pr[1], x2 = pr[2], y2 = pr[3];
    float w = x2 - x1, h = y2 - y1;
    float cx = x1 + 0.5f * w, cy = y1 + 0.5f * h;
    const float* r = box_reg + (size_t)row * (C_ * 4) + cls * 4;
    float dx = r[0] / 10.f, dy = r[1] / 10.f;
    float dw = fminf(r[2] / 5.f, BBOX_CLIP);
    float dh = fminf(r[3] / 5.f, BBOX_CLIP);
    float pcx = dx * w + cx, pcy = dy * h + cy;
    float pw = expf(dw) * w, ph = expf(dh) * h;
    o[0] = fminf(fmaxf(pcx - 0.5f * pw, 0.f), IMG_W_);
    o[1] = fminf(fmaxf(pcy - 0.5f * ph, 0.f), IMG_H_);
    o[2] = fminf(fmaxf(pcx + 0.5f * pw, 0.f), IMG_W_);
    o[3] = fminf(fmaxf(pcy + 0.5f * ph, 0.f), IMG_H_);
}

__device__ __forceinline__ void emit_det(int b, int k, u64 key,
                                         const float* __restrict__ box_reg,
                                         const float* __restrict__ props,
                                         float* __restrict__ out) {
    float* ob = out + (b * K_ + k) * 4;
    if (key == 0) {
        ob[0] = 0.f; ob[1] = 0.f; ob[2] = 0.f; ob[3] = 0.f;
        out[3200 + b * K_ + k] = 0.f;
        out[4000 + b * K_ + k] = 0.f;
        return;
    }
    u32 sb = (u32)(key >> 27);
    int flat = 0x1FFFF - (int)((key >> 10) & 0x1FFFF);
    int n = (int)(key & 1023);
    int c = flat / 1000;   // class-1
    float bx[4];
    decode_box(box_reg, props, b * N_ + n, c + 1, bx);
    ob[0] = bx[0]; ob[1] = bx[1]; ob[2] = bx[2]; ob[3] = bx[3];
    out[3200 + b * K_ + k] = __uint_as_float(sb);
    out[4000 + b * K_ + k] = (float)(c + 1);
}

// ------------- Kernel 1: wave-per-row softmax + threshold + per-class compaction -------------
// 1000 blocks x 4 waves x 2 rows = 8000 rows (2 rows/wave for ILP, half the blocks)
__global__ __launch_bounds__(256) void k_score(const float* __restrict__ logits,
                                               u64* __restrict__ pc_keys) {
    int wave = threadIdx.x >> 6, lane = threadIdx.x & 63;
    int row0 = blockIdx.x * 8 + wave * 2;
    #pragma unroll
    for (int r = 0; r < 2; ++r) {
        int row = row0 + r;                          // [0, 8000)
        const float* lg = logits + row * C_;
        float v0 = lg[lane];
        float v1 = (lane < C_ - 64) ? lg[lane + 64] : -INFINITY;
        float m = fmaxf(v0, v1);
        #pragma unroll
        for (int o = 32; o; o >>= 1) m = fmaxf(m, __shfl_xor(m, o));
        float e0 = expf(v0 - m);
        float e1 = (lane < C_ - 64) ? expf(v1 - m) : 0.f;
        float s = e0 + e1;
        #pragma unroll
        for (int o = 32; o; o >>= 1) s += __shfl_xor(s, o);
        float inv = 1.f / s;
        int b = row / N_, n = row % N_;
        float s0 = e0 * inv;            // class = lane (lane>=1; lane 0 is background)
        if (lane >= 1 && s0 > SCORE_TH) {
            int idx = b * NC + (lane - 1);
            int p = atomicAdd(&g_pc_cnt[idx], 1);
            pc_keys[(size_t)idx * 1000 + p] =
                ((u64)__float_as_uint(s0) << 10) | (u32)(1023 - n);
        }
        float s1 = e1 * inv;            // class = lane + 64
        if (lane < C_ - 64 && s1 > SCORE_TH) {
            int idx = b * NC + (lane + 63);
            int p = atomicAdd(&g_pc_cnt[idx], 1);
            pc_keys[(size_t)idx * 1000 + p] =
                ((u64)__float_as_uint(s1) << 10) | (u32)(1023 - n);
        }
    }
}

// ------------- Kernel 2: per-(b,class) single-wave sort + register NMS -------------
__global__ __launch_bounds__(64) void k_nms(const u64* __restrict__ pc_keys,
                                            const float* __restrict__ box_reg,
                                            const float* __restrict__ props,
                                            u64* __restrict__ gkeys) {
    int bc = blockIdx.x;
    int b = bc / NC, c = bc % NC;   // class id = c+1
    int lane = threadIdx.x;
    int cnt = g_pc_cnt[bc];
    const u64* pk = pc_keys + (size_t)bc * 1000;

    __shared__ u64 skeys[1024];
    __shared__ float sbx[1024][4];
    __shared__ unsigned char skeep[1024];

    if (cnt <= 64) {
        // ---- fast path: registers only, zero barriers ----
        u64 key = (lane < cnt) ? pk[lane] : 0;
        #pragma unroll
        for (int k2 = 2; k2 <= 64; k2 <<= 1) {
            #pragma unroll
            for (int j = k2 >> 1; j; j >>= 1) {
                u64 p = __shfl_xor(key, j);
                bool takeMax = ((lane & j) == 0) == ((lane & k2) == 0);
                bool greater = key > p;
                key = (takeMax == greater) ? key : p;
            }
        }
        float x1 = 0.f, y1 = 0.f, x2 = 0.f, y2 = 0.f, area = 0.f;
        int n = 1023 - (int)(key & 1023);
        u32 sb = (u32)(key >> 10);
        if (lane < cnt) {
            float bx[4];
            decode_box(box_reg, props, b * N_ + n, c + 1, bx);
            x1 = bx[0]; y1 = bx[1]; x2 = bx[2]; y2 = bx[3];
            area = (x2 - x1) * (y2 - y1);
        }
        u64 keepm = (cnt >= 64) ? ~0ull : ((1ull << cnt) - 1ull);
        for (int i = 0; i < cnt; ++i) {
            if (!((keepm >> i) & 1ull)) continue;
            float ax1 = __shfl(x1, i), ay1 = __shfl(y1, i);
            float ax2 = __shfl(x2, i), ay2 = __shfl(y2, i);
            float aarea = __shfl(area, i);
            float lx = fmaxf(ax1, x1), ly = fmaxf(ay1, y1);
            float rx = fminf(ax2, x2), ry = fminf(ay2, y2);
            float iw = fmaxf(rx - lx, 0.f), ih = fmaxf(ry - ly, 0.f);
            float inter = iw * ih;
            float iou = inter / (aarea + area - inter + 1e-9f);
            bool sup = (lane > i) && (lane < cnt) && (iou > NMS_TH);
            keepm &= ~__ballot(sup);
        }
        int total = __popcll(keepm);
        int base = 0;
        if (lane == 0 && total) base = atomicAdd(&g_counts[b], total);
        base = __shfl(base, 0);
        if ((keepm >> lane) & 1ull) {
            int off = __popcll(keepm & ((1ull << lane) - 1ull));
            int flat = c * 1000 + lane;
            gkeys[(size_t)b * CAP + base + off] =
                ((u64)sb << 27) | ((u64)(0x1FFFF - flat) << 10) | (u32)n;
        }
    } else {
        // ---- cold path: LDS bitonic over 1024, sequential NMS ----
        for (int i = lane; i < 1024; i += 64) skeys[i] = (i < cnt) ? pk[i] : 0;
        __syncthreads();
        for (int k2 = 2; k2 <= 1024; k2 <<= 1) {
            for (int j = k2 >> 1; j; j >>= 1) {
                for (int i = lane; i < 1024; i += 64) {
                    int ixj = i ^ j;
                    if (ixj > i) {
                        u64 a = skeys[i], bb2 = skeys[ixj];
                        bool desc = ((i & k2) == 0);
                        if (desc ? (a < bb2) : (a > bb2)) { skeys[i] = bb2; skeys[ixj] = a; }
                    }
                }
                __syncthreads();
            }
        }
        for (int i = lane; i < cnt; i += 64) {
            u64 key = skeys[i];
            int n = 1023 - (int)(key & 1023);
            decode_box(box_reg, props, b * N_ + n, c + 1, sbx[i]);
            skeep[i] = 1;
        }
        __syncthreads();
        for (int i = 0; i < cnt; ++i) {
            if (skeep[i]) {
                float ax1 = sbx[i][0], ay1 = sbx[i][1], ax2 = sbx[i][2], ay2 = sbx[i][3];
                float a1 = (ax2 - ax1) * (ay2 - ay1);
                for (int j = i + 1 + lane; j < cnt; j += 64) {
                    float lx = fmaxf(ax1, sbx[j][0]), ly = fmaxf(ay1, sbx[j][1]);
                    float rx = fminf(ax2, sbx[j][2]), ry = fminf(ay2, sbx[j][3]);
                    float iw = fmaxf(rx - lx, 0.f), ih = fmaxf(ry - ly, 0.f);
                    float inter = iw * ih;
                    float a2 = (sbx[j][2] - sbx[j][0]) * (sbx[j][3] - sbx[j][1]);
                    float iou = inter / (a1 + a2 - inter + 1e-9f);
                    if (iou > NMS_TH) skeep[j] = 0;
                }
            }
            __syncthreads();
        }
        for (int i = lane; i < cnt; i += 64) {
            if (skeep[i]) {
                int p2 = atomicAdd(&g_counts[b], 1);
                u64 key = skeys[i];
                u32 sb = (u32)(key >> 10);
                int n = 1023 - (int)(key & 1023);
                int flat = c * 1000 + i;
                gkeys[(size_t)b * CAP + p2] =
                    ((u64)sb << 27) | ((u64)(0x1FFFF - flat) << 10) | (u32)n;
            }
        }
    }
}

// ------------- single-wave in-register bitonic (descending), SS = R*64 -------------
// element index i = (r<<6)|lane. j>=64 exchanges are compile-time register pairs
// (no runtime register indexing -> no scratch); j<64 exchanges via shfl_xor.
template <int R, int JR>
__device__ __forceinline__ void reg_step(u64 (&k)[R], int k2, int lane) {
    #pragma unroll
    for (int r = 0; r < R; ++r) {
        if ((r & JR) == 0 && (r | JR) < R) {
            const int r2 = r | JR;
            int i = (r << 6) | lane;
            bool desc = (i & k2) == 0;
            u64 a = k[r], bb = k[r2];
            if (desc ? (a < bb) : (a > bb)) { k[r] = bb; k[r2] = a; }
        }
    }
}

template <int R>
__device__ __forceinline__ void wave_sort_topk(u64* comp, int cc, int lane) {
    u64 k[R];
    #pragma unroll
    for (int r = 0; r < R; ++r) {
        int idx = (r << 6) | lane;
        k[r] = (idx < cc) ? comp[idx] : 0ull;
    }
    const int SS = R * 64;
    #pragma unroll
    for (int k2 = 2; k2 <= SS; k2 <<= 1) {
        if (k2 >= 512) reg_step<R, 4>(k, k2, lane);   // j = 256
        if (k2 >= 256) reg_step<R, 2>(k, k2, lane);   // j = 128
        if (k2 >= 128) reg_step<R, 1>(k, k2, lane);   // j = 64
        for (int j = (k2 > 64 ? 32 : (k2 >> 1)); j > 0; j >>= 1) {
            #pragma unroll
            for (int r = 0; r < R; ++r) {
                u64 p = __shfl_xor(k[r], j);
                int i = (r << 6) | lane;
                bool lower = (lane & j) == 0;
                bool desc = (i & k2) == 0;
                u64 mx = k[r] > p ? k[r] : p;
                u64 mn = k[r] > p ? p : k[r];
                k[r] = (lower == desc) ? mx : mn;
            }
        }
    }
    // write back top-128 (covers K_=100); rest of comp is never read
    comp[lane] = k[0];
    comp[64 | lane] = k[1];
}

// ------------- Kernel 3: per-image top-K via histogram select + small sort -------------
// No LDS staging of the survivor list: it is ~16 KB/image and L2-resident, so the
// histogram pass and the compaction pass just read gkeys twice.
__global__ __launch_bounds__(256) void k_topk(u64* __restrict__ gkeys,
                                              const float* __restrict__ box_reg,
                                              const float* __restrict__ props,
                                              float* __restrict__ out) {
    int b = blockIdx.x;
    int tid = threadIdx.x;
    int cnt = g_counts[b];
    if (cnt > CAP) cnt = CAP;
    __shared__ u64 comp[2048];
    __shared__ int hist[NBUCKET];
    __shared__ int sT, sCompCnt;
    __shared__ u64 wk[4];
    __shared__ int wp[4];
    u64* gk = gkeys + (size_t)b * CAP;

    for (int i = tid; i < NBUCKET; i += 256) hist[i] = 0;
    if (tid == 0) sCompCnt = 0;
    __syncthreads();
    // pass A: histogram of the monotone 15-bit score prefix (key>>44)
    for (int i = tid; i < cnt; i += 256) {
        int bk = (int)(gk[i] >> 44) - BUCKET_BASE;
        bk = min(max(bk, 0), NBUCKET - 1);
        atomicAdd(&hist[bk], 1);
    }
    __syncthreads();
    // single-wave suffix scan from top bucket: smallest T with count(bucket>=T) >= K
    if (tid < 64) {
        int lane = tid;
        int running = 0, T = 0;
        for (int step = 0; step < NBUCKET / 64; ++step) {
            int bucket = NBUCKET - 1 - (step * 64 + lane);
            int v = hist[bucket];
            #pragma unroll
            for (int o = 1; o < 64; o <<= 1) {
                int t = __shfl_up(v, o);
                if (lane >= o) v += t;
            }
            int cum = running + v;
            u64 mask = __ballot(cum >= K_);
            if (mask) {
                int fl = __ffsll(mask) - 1;   // first (highest-bucket) crossing
                T = NBUCKET - 1 - (step * 64 + fl);
                break;
            }
            running = __shfl(cum, 63);
        }
        if (tid == 0) sT = T;
    }
    __syncthreads();
    int T = sT;
    // pass B: compact keys with bucket >= T (superset of top-K, typically ~100-300)
    for (int i = tid; i < cnt; i += 256) {
        u64 key = gk[i];
        int bk = (int)(key >> 44) - BUCKET_BASE;
        bk = min(max(bk, 0), NBUCKET - 1);
        if (bk >= T) {
            int p = atomicAdd(&sCompCnt, 1);
            if (p < 2048) comp[p] = key;
        }
    }
    __syncthreads();
    int cc = sCompCnt;
    if (cc <= 2048) {
        if (cc <= 128) {
            if (tid < 64) wave_sort_topk<2>(comp, cc, tid);
        } else if (cc <= 256) {
            if (tid < 64) wave_sort_topk<4>(comp, cc, tid);
        } else if (cc <= 512) {
            if (tid < 64) wave_sort_topk<8>(comp, cc, tid);
        } else {
            // rare: 4-wave LDS bitonic over 1024/2048
            int SS = (cc > 1024) ? 2048 : 1024;
            for (int i = cc + tid; i < SS; i += 256) comp[i] = 0;
            __syncthreads();
            for (int k2 = 2; k2 <= SS; k2 <<= 1) {
                for (int j = k2 >> 1; j; j >>= 1) {
                    for (int i = tid; i < SS; i += 256) {
                        int ixj = i ^ j;
                        if (ixj > i) {
                            u64 a = comp[i], bb2 = comp[ixj];
                            bool desc = ((i & k2) == 0);
                            if (desc ? (a < bb2) : (a > bb2)) { comp[i] = bb2; comp[ixj] = a; }
                        }
                    }
                    __syncthreads();
                }
            }
        }
        __syncthreads();
        if (tid < K_) emit_det(b, tid, comp[tid], box_reg, props, out);
    } else {
        // improbable fallback: destructive iterative argmax over the global list
        for (int k = 0; k < K_; ++k) {
            u64 best = 0; int bpos = 0;
            for (int i = tid; i < cnt; i += 256) {
                u64 v = gk[i];
                if (v > best) { best = v; bpos = i; }
            }
            for (int o = 32; o; o >>= 1) {
                u64 ov = __shfl_down(best, o);
                int op = __shfl_down(bpos, o);
                if (ov > best) { best = ov; bpos = op; }
            }
            if ((tid & 63) == 0) { wk[tid >> 6] = best; wp[tid >> 6] = bpos; }
            __syncthreads();
            if (tid == 0) {
                for (int w2 = 1; w2 < 4; ++w2)
                    if (wk[w2] > best) { best = wk[w2]; bpos = wp[w2]; }
                emit_det(b, k, best, box_reg, props, out);
                if (best) gk[bpos] = 0;
            }
            __threadfence();
            __syncthreads();
        }
    }

    // reset persistent counters for the next launch (all consumers done:
    // g_pc_cnt was read by k_nms, g_counts[b] was read at this kernel's start)
    for (int i = tid; i < NC; i += 256) g_pc_cnt[b * NC + i] = 0;
    if (tid == 0) g_counts[b] = 0;
}

// ------------- Kernel 4: mask sigmoid gather (float4) -------------
__global__ __launch_bounds__(256) void k_mask(const float* __restrict__ mask_logits,
                                              float* __restrict__ out) {
    int idx = blockIdx.x * 256 + threadIdx.x;      // over B*K*196 float4s
    if (idx >= B_ * K_ * 196) return;
    int p = idx % 196;
    int bk = idx / 196;                            // b*K + k
    int label = (int)out[4000 + bk];               // exact small-int float
    const float4* src = (const float4*)mask_logits;
    float4 v = src[((size_t)bk * C_ + label) * 196 + p];
    float4 r;
    r.x = 1.f / (1.f + expf(-v.x));
    r.y = 1.f / (1.f + expf(-v.y));
    r.z = 1.f / (1.f + expf(-v.z));
    r.w = 1.f / (1.f + expf(-v.w));
    ((float4*)(out + 4800))[idx] = r;
}

extern "C" void kernel_launch(void* const* d_in, const int* in_sizes, int n_in,
                              void* d_out, int out_size, void* d_ws, size_t ws_size,
                              hipStream_t stream) {
    const float* logits   = (const float*)d_in[0];  // [B*N, C]
    const float* box_reg  = (const float*)d_in[1];  // [B*N, C*4]
    const float* props    = (const float*)d_in[2];  // [B, N, 4]
    const float* mask_log = (const float*)d_in[3];  // [B, K, C, M, M]
    float* out = (float*)d_out;

    char* ws = (char*)d_ws;
    u64* gkeys   = (u64*)ws;                  // 8*80000 u64
    u64* pc_keys = (u64*)(ws + 5120000);      // 640*1000 u64

    k_score<<<1000, 256, 0, stream>>>(logits, pc_keys);
    k_nms<<<B_ * NC, 64, 0, stream>>>(pc_keys, box_reg, props, gkeys);
    k_topk<<<B_, 256, 0, stream>>>(gkeys, box_reg, props, out);
    k_mask<<<(B_ * K_ * 196 + 255) / 256, 256, 0, stream>>>(mask_log, out);
}